// Round 1
// baseline (524.608 us; speedup 1.0000x reference)
//
#include <hip/hip_runtime.h>
#include <hip/hip_bf16.h>

#define N_NODES 8192
#define N_EDGES 262144
// F_IN=512, H1=256, H2=128 (x2 fused = 256), H3=64, OUT6=6

// ---------------- CSR build (counting sort by row) ----------------
__global__ void k_hist(const int* __restrict__ rows, int* __restrict__ counts) {
    int e = blockIdx.x * 256 + threadIdx.x;
    if (e < N_EDGES) atomicAdd(&counts[rows[e]], 1);
}

__global__ void k_scan(const int* __restrict__ counts, int* __restrict__ offs) {
    __shared__ int part[1024];
    int t = threadIdx.x;
    int base = t * 8;
    int loc[8];
    int s = 0;
#pragma unroll
    for (int i = 0; i < 8; i++) { loc[i] = s; s += counts[base + i]; }
    part[t] = s;
    __syncthreads();
    for (int off = 1; off < 1024; off <<= 1) {
        int v = (t >= off) ? part[t - off] : 0;
        __syncthreads();
        part[t] += v;
        __syncthreads();
    }
    int prev = (t == 0) ? 0 : part[t - 1];
#pragma unroll
    for (int i = 0; i < 8; i++) offs[base + i] = prev + loc[i];
    if (t == 1023) offs[N_NODES] = part[1023];
}

__global__ void k_scatter(const int* __restrict__ rows, const int* __restrict__ colsIn,
                          const float* __restrict__ valsIn, const int* __restrict__ offs,
                          int* __restrict__ cursor, int* __restrict__ colsOut,
                          float* __restrict__ valsOut) {
    int e = blockIdx.x * 256 + threadIdx.x;
    if (e >= N_EDGES) return;
    int r = rows[e];
    int p = atomicAdd(&cursor[r], 1);
    int idx = offs[r] + p;
    colsOut[idx] = colsIn[e];
    valsOut[idx] = valsIn[e];
}

// ---------------- W23 = [W2 | W3]  (256 x 256) ----------------
__global__ void k_concat_w23(const float* __restrict__ W2, const float* __restrict__ W3,
                             float* __restrict__ W23) {
    int i = blockIdx.x * 256 + threadIdx.x;  // 0..65535
    int k = i >> 8, j = i & 255;
    W23[i] = (j < 128) ? W2[k * 128 + j] : W3[k * 128 + (j - 128)];
}

// ---------------- generic fp32 tiled GEMM: C = A(MxK) * B(KxN) [+bias] ----------------
// BM=BN=64, BK=16, 16x16 threads, 4x4 per thread. M mult of 64, N mult of 64, K mult of 16.
__global__ __launch_bounds__(256) void k_gemm(const float* __restrict__ A, int lda,
                                              const float* __restrict__ B, int ldb,
                                              float* __restrict__ C, int ldc, int K,
                                              const float* __restrict__ bias) {
    __shared__ float sA[16][68];  // [k][m] transposed
    __shared__ float sB[16][68];  // [k][n]
    int tx = threadIdx.x, ty = threadIdx.y;
    int t = ty * 16 + tx;
    int row0 = blockIdx.y * 64, col0 = blockIdx.x * 64;
    int am = t >> 2, ak = (t & 3) * 4;
    int bk = t >> 4, bn = (t & 15) * 4;
    float acc[4][4] = {};
    for (int k0 = 0; k0 < K; k0 += 16) {
        float4 av = *(const float4*)&A[(size_t)(row0 + am) * lda + k0 + ak];
        float4 bv = *(const float4*)&B[(size_t)(k0 + bk) * ldb + col0 + bn];
        sA[ak + 0][am] = av.x; sA[ak + 1][am] = av.y;
        sA[ak + 2][am] = av.z; sA[ak + 3][am] = av.w;
        *(float4*)&sB[bk][bn] = bv;
        __syncthreads();
#pragma unroll
        for (int k = 0; k < 16; k++) {
            float4 a4 = *(const float4*)&sA[k][ty * 4];
            float4 b4 = *(const float4*)&sB[k][tx * 4];
            float ar[4] = {a4.x, a4.y, a4.z, a4.w};
            float br[4] = {b4.x, b4.y, b4.z, b4.w};
#pragma unroll
            for (int a = 0; a < 4; a++)
#pragma unroll
                for (int b = 0; b < 4; b++) acc[a][b] += ar[a] * br[b];
        }
        __syncthreads();
    }
#pragma unroll
    for (int a = 0; a < 4; a++) {
        int row = row0 + ty * 4 + a;
        int col = col0 + tx * 4;
        float4 r = make_float4(acc[a][0], acc[a][1], acc[a][2], acc[a][3]);
        if (bias) { r.x += bias[col]; r.y += bias[col + 1]; r.z += bias[col + 2]; r.w += bias[col + 3]; }
        *(float4*)&C[(size_t)row * ldc + col] = r;
    }
}

// ---------------- SpMM (CSR), D=256, optional relu ----------------
__global__ __launch_bounds__(256) void k_spmm(const int* __restrict__ offs,
                                              const int* __restrict__ cols,
                                              const float* __restrict__ vals,
                                              const float* __restrict__ in,
                                              float* __restrict__ out, int relu) {
    const int row = blockIdx.x;
    const int d = threadIdx.x;
    int s = offs[row], e = offs[row + 1];
    float acc = 0.f;
    __shared__ int sc[256];
    __shared__ float sv[256];
    for (int base = s; base < e; base += 256) {
        int n = e - base;
        if (n > 256) n = 256;
        int idx = base + threadIdx.x;
        if (threadIdx.x < n) { sc[threadIdx.x] = cols[idx]; sv[threadIdx.x] = vals[idx]; }
        __syncthreads();
        for (int i = 0; i < n; i++) acc += sv[i] * in[(size_t)sc[i] * 256 + d];
        __syncthreads();
    }
    out[(size_t)row * 256 + d] = relu ? fmaxf(acc, 0.f) : acc;
}

// ---------------- out6 = Z(8192x64) @ W(64x6) + b ----------------
__global__ __launch_bounds__(256) void k_out6(const float* __restrict__ Z,
                                              const float* __restrict__ W,
                                              const float* __restrict__ b,
                                              float* __restrict__ out) {
    __shared__ float sW[384];
    int t = threadIdx.x;
    for (int i = t; i < 384; i += 256) sW[i] = W[i];
    __syncthreads();
    int row = blockIdx.x * 256 + t;
    float acc[6];
#pragma unroll
    for (int j = 0; j < 6; j++) acc[j] = b[j];
    for (int k = 0; k < 64; k++) {
        float zv = Z[(size_t)row * 64 + k];
#pragma unroll
        for (int j = 0; j < 6; j++) acc[j] += zv * sW[k * 6 + j];
    }
#pragma unroll
    for (int j = 0; j < 6; j++) out[(size_t)row * 6 + j] = acc[j];
}

// ---------------- adj_rec = Z @ Z^T  (8192x8192, K=64) ----------------
__global__ __launch_bounds__(256) void k_zzt(const float* __restrict__ Z, float* __restrict__ C) {
    __shared__ float sA[64][72];  // [k][m]
    __shared__ float sB[64][72];  // [k][n]
    int tx = threadIdx.x, ty = threadIdx.y;
    int t = ty * 16 + tx;
    int I = blockIdx.y * 64, J = blockIdx.x * 64;
    int r = t >> 2, q = (t & 3) * 16;
#pragma unroll
    for (int j = 0; j < 16; j += 4) {
        float4 v = *(const float4*)&Z[(size_t)(I + r) * 64 + q + j];
        sA[q + j + 0][r] = v.x; sA[q + j + 1][r] = v.y;
        sA[q + j + 2][r] = v.z; sA[q + j + 3][r] = v.w;
    }
#pragma unroll
    for (int j = 0; j < 16; j += 4) {
        float4 v = *(const float4*)&Z[(size_t)(J + r) * 64 + q + j];
        sB[q + j + 0][r] = v.x; sB[q + j + 1][r] = v.y;
        sB[q + j + 2][r] = v.z; sB[q + j + 3][r] = v.w;
    }
    __syncthreads();
    float acc[4][4] = {};
#pragma unroll
    for (int k = 0; k < 64; k++) {
        float4 a4 = *(const float4*)&sA[k][ty * 4];
        float4 b4 = *(const float4*)&sB[k][tx * 4];
        float ar[4] = {a4.x, a4.y, a4.z, a4.w};
        float br[4] = {b4.x, b4.y, b4.z, b4.w};
#pragma unroll
        for (int a = 0; a < 4; a++)
#pragma unroll
            for (int b = 0; b < 4; b++) acc[a][b] += ar[a] * br[b];
    }
#pragma unroll
    for (int a = 0; a < 4; a++) {
        int row = I + ty * 4 + a;
        *(float4*)&C[(size_t)row * 8192 + J + tx * 4] =
            make_float4(acc[a][0], acc[a][1], acc[a][2], acc[a][3]);
    }
}

extern "C" void kernel_launch(void* const* d_in, const int* in_sizes, int n_in,
                              void* d_out, int out_size, void* d_ws, size_t ws_size,
                              hipStream_t stream) {
    const float* x        = (const float*)d_in[0];
    const int*   adj_rows = (const int*)d_in[1];
    const int*   adj_cols = (const int*)d_in[2];
    const float* adj_vals = (const float*)d_in[3];
    const float* W1       = (const float*)d_in[4];
    const float* W2       = (const float*)d_in[5];
    const float* W3       = (const float*)d_in[6];
    const float* dense_W  = (const float*)d_in[7];
    const float* dense_b  = (const float*)d_in[8];
    const float* dense1_W = (const float*)d_in[9];
    const float* dense1_b = (const float*)d_in[10];

    // workspace layout
    char* p = (char*)d_ws;
    int* counts = (int*)p;   p += 8192 * 4;
    int* cursor = (int*)p;   p += 8192 * 4;
    int* offs   = (int*)p;   p += 8224 * 4;   // 8193 used, padded
    int* scol   = (int*)p;   p += (size_t)N_EDGES * 4;
    float* sval = (float*)p; p += (size_t)N_EDGES * 4;
    float* XW1  = (float*)p; p += (size_t)8192 * 256 * 4;
    float* Hid  = (float*)p; p += (size_t)8192 * 256 * 4;
    float* Tb   = (float*)p; p += (size_t)8192 * 256 * 4;
    float* Mb   = (float*)p; p += (size_t)8192 * 256 * 4;
    float* W23  = (float*)p; p += (size_t)256 * 256 * 4;

    // output layout: adj_rec [8192x8192], out6 [8192x6], mu [8192x64], logvar [8192x64]
    float* out     = (float*)d_out;
    float* adj_rec = out;
    float* out6    = out + (size_t)8192 * 8192;
    float* mu      = out6 + (size_t)8192 * 6;
    float* logvar  = mu + (size_t)8192 * 64;

    dim3 blk(16, 16);

    hipMemsetAsync(counts, 0, 2 * 8192 * 4, stream);  // counts + cursor
    k_hist<<<N_EDGES / 256, 256, 0, stream>>>(adj_rows, counts);
    k_scan<<<1, 1024, 0, stream>>>(counts, offs);
    k_scatter<<<N_EDGES / 256, 256, 0, stream>>>(adj_rows, adj_cols, adj_vals, offs, cursor,
                                                 scol, sval);
    k_concat_w23<<<256, 256, 0, stream>>>(W2, W3, W23);

    // XW1 = x @ W1
    k_gemm<<<dim3(4, 128), blk, 0, stream>>>(x, 512, W1, 256, XW1, 256, 512, nullptr);
    // hidden1 = relu(spmm(XW1))
    k_spmm<<<8192, 256, 0, stream>>>(offs, scol, sval, XW1, Hid, 1);
    // T = hidden1 @ [W2|W3]
    k_gemm<<<dim3(4, 128), blk, 0, stream>>>(Hid, 256, W23, 256, Tb, 256, 256, nullptr);
    // M = spmm(T)  -> [mu0 | logvar0]
    k_spmm<<<8192, 256, 0, stream>>>(offs, scol, sval, Tb, Mb, 0);
    // mu = M[:, :128] @ dense_W + dense_b ; logvar = M[:, 128:] @ dense_W + dense_b
    k_gemm<<<dim3(1, 128), blk, 0, stream>>>(Mb, 256, dense_W, 64, mu, 64, 128, dense_b);
    k_gemm<<<dim3(1, 128), blk, 0, stream>>>(Mb + 128, 256, dense_W, 64, logvar, 64, 128, dense_b);
    // out6 = mu @ dense1_W + dense1_b
    k_out6<<<32, 256, 0, stream>>>(mu, dense1_W, dense1_b, out6);
    // adj_rec = mu @ mu^T
    k_zzt<<<dim3(128, 128), blk, 0, stream>>>(mu, adj_rec);
}

// Round 2
// 465.511 us; speedup vs baseline: 1.1270x; 1.1270x over previous
//
#include <hip/hip_runtime.h>
#include <hip/hip_bf16.h>

#define N_NODES 8192
#define N_EDGES 262144
// F_IN=512, H1=256, H2=128 (x2 fused = 256), H3=64, OUT6=6

typedef __attribute__((ext_vector_type(8))) short short8;
typedef __attribute__((ext_vector_type(4))) float f32x4;

// ---------------- CSR build (counting sort by row) ----------------
__global__ void k_hist(const int* __restrict__ rows, int* __restrict__ counts) {
    int e = blockIdx.x * 256 + threadIdx.x;
    if (e < N_EDGES) atomicAdd(&counts[rows[e]], 1);
}

__global__ void k_scan(const int* __restrict__ counts, int* __restrict__ offs) {
    __shared__ int part[1024];
    int t = threadIdx.x;
    int base = t * 8;
    int loc[8];
    int s = 0;
#pragma unroll
    for (int i = 0; i < 8; i++) { loc[i] = s; s += counts[base + i]; }
    part[t] = s;
    __syncthreads();
    for (int off = 1; off < 1024; off <<= 1) {
        int v = (t >= off) ? part[t - off] : 0;
        __syncthreads();
        part[t] += v;
        __syncthreads();
    }
    int prev = (t == 0) ? 0 : part[t - 1];
#pragma unroll
    for (int i = 0; i < 8; i++) offs[base + i] = prev + loc[i];
    if (t == 1023) offs[N_NODES] = part[1023];
}

__global__ void k_scatter(const int* __restrict__ rows, const int* __restrict__ colsIn,
                          const float* __restrict__ valsIn, const int* __restrict__ offs,
                          int* __restrict__ cursor, int* __restrict__ colsOut,
                          float* __restrict__ valsOut) {
    int e = blockIdx.x * 256 + threadIdx.x;
    if (e >= N_EDGES) return;
    int r = rows[e];
    int p = atomicAdd(&cursor[r], 1);
    int idx = offs[r] + p;
    colsOut[idx] = colsIn[e];
    valsOut[idx] = valsIn[e];
}

// ---------------- W23 = [W2 | W3]  (256 x 256) ----------------
__global__ void k_concat_w23(const float* __restrict__ W2, const float* __restrict__ W3,
                             float* __restrict__ W23) {
    int i = blockIdx.x * 256 + threadIdx.x;  // 0..65535
    int k = i >> 8, j = i & 255;
    W23[i] = (j < 128) ? W2[k * 128 + j] : W3[k * 128 + (j - 128)];
}

// ---------------- generic fp32 tiled GEMM: C = A(MxK) * B(KxN) [+bias] ----------------
__global__ __launch_bounds__(256) void k_gemm(const float* __restrict__ A, int lda,
                                              const float* __restrict__ B, int ldb,
                                              float* __restrict__ C, int ldc, int K,
                                              const float* __restrict__ bias) {
    __shared__ float sA[16][68];  // [k][m] transposed
    __shared__ float sB[16][68];  // [k][n]
    int tx = threadIdx.x, ty = threadIdx.y;
    int t = ty * 16 + tx;
    int row0 = blockIdx.y * 64, col0 = blockIdx.x * 64;
    int am = t >> 2, ak = (t & 3) * 4;
    int bk = t >> 4, bn = (t & 15) * 4;
    float acc[4][4] = {};
    for (int k0 = 0; k0 < K; k0 += 16) {
        float4 av = *(const float4*)&A[(size_t)(row0 + am) * lda + k0 + ak];
        float4 bv = *(const float4*)&B[(size_t)(k0 + bk) * ldb + col0 + bn];
        sA[ak + 0][am] = av.x; sA[ak + 1][am] = av.y;
        sA[ak + 2][am] = av.z; sA[ak + 3][am] = av.w;
        *(float4*)&sB[bk][bn] = bv;
        __syncthreads();
#pragma unroll
        for (int k = 0; k < 16; k++) {
            float4 a4 = *(const float4*)&sA[k][ty * 4];
            float4 b4 = *(const float4*)&sB[k][tx * 4];
            float ar[4] = {a4.x, a4.y, a4.z, a4.w};
            float br[4] = {b4.x, b4.y, b4.z, b4.w};
#pragma unroll
            for (int a = 0; a < 4; a++)
#pragma unroll
                for (int b = 0; b < 4; b++) acc[a][b] += ar[a] * br[b];
        }
        __syncthreads();
    }
#pragma unroll
    for (int a = 0; a < 4; a++) {
        int row = row0 + ty * 4 + a;
        int col = col0 + tx * 4;
        float4 r = make_float4(acc[a][0], acc[a][1], acc[a][2], acc[a][3]);
        if (bias) { r.x += bias[col]; r.y += bias[col + 1]; r.z += bias[col + 2]; r.w += bias[col + 3]; }
        *(float4*)&C[(size_t)row * ldc + col] = r;
    }
}

// ---------------- SpMM (CSR), D=256, optional relu ----------------
__global__ __launch_bounds__(256) void k_spmm(const int* __restrict__ offs,
                                              const int* __restrict__ cols,
                                              const float* __restrict__ vals,
                                              const float* __restrict__ in,
                                              float* __restrict__ out, int relu) {
    const int row = blockIdx.x;
    const int d = threadIdx.x;
    int s = offs[row], e = offs[row + 1];
    float acc = 0.f;
    __shared__ int sc[256];
    __shared__ float sv[256];
    for (int base = s; base < e; base += 256) {
        int n = e - base;
        if (n > 256) n = 256;
        int idx = base + threadIdx.x;
        if (threadIdx.x < n) { sc[threadIdx.x] = cols[idx]; sv[threadIdx.x] = vals[idx]; }
        __syncthreads();
        for (int i = 0; i < n; i++) acc += sv[i] * in[(size_t)sc[i] * 256 + d];
        __syncthreads();
    }
    out[(size_t)row * 256 + d] = relu ? fmaxf(acc, 0.f) : acc;
}

// ---------------- out6 = Z(8192x64) @ W(64x6) + b ----------------
__global__ __launch_bounds__(256) void k_out6(const float* __restrict__ Z,
                                              const float* __restrict__ W,
                                              const float* __restrict__ b,
                                              float* __restrict__ out) {
    __shared__ float sW[384];
    int t = threadIdx.x;
    for (int i = t; i < 384; i += 256) sW[i] = W[i];
    __syncthreads();
    int row = blockIdx.x * 256 + t;
    float acc[6];
#pragma unroll
    for (int j = 0; j < 6; j++) acc[j] = b[j];
    for (int k = 0; k < 64; k++) {
        float zv = Z[(size_t)row * 64 + k];
#pragma unroll
        for (int j = 0; j < 6; j++) acc[j] += zv * sW[k * 6 + j];
    }
#pragma unroll
    for (int j = 0; j < 6; j++) out[(size_t)row * 6 + j] = acc[j];
}

// ---------------- fp32 -> bf16 convert ----------------
__global__ void k_f32_to_bf16(const float* __restrict__ in, __hip_bfloat16* __restrict__ out,
                              int n) {
    int i = blockIdx.x * 256 + threadIdx.x;
    if (i < n) out[i] = __float2bfloat16(in[i]);
}

// ---------------- adj_rec = Z @ Z^T via bf16 MFMA ----------------
// Block = 256 thr = 4 waves, block tile 128x128, wave tile 64x64.
// Z is 8192x64 bf16 (1 MB, L2-resident) -> fragments loaded straight from global.
__global__ __launch_bounds__(256) void k_zzt_mfma(const __hip_bfloat16* __restrict__ Zh,
                                                  float* __restrict__ C) {
    int t = threadIdx.x;
    int lane = t & 63;
    int w = t >> 6;  // wave 0..3
    int I = blockIdx.y * 128 + (w >> 1) * 64;
    int J = blockIdx.x * 128 + (w & 1) * 64;
    int r = lane & 15;
    int koff = (lane >> 4) * 8;  // quad*8

    // a[m][kk]: A[m*16 + (lane&15)][kk*32 + quad*8 + j]   (Z rows I..)
    // b[n][kk]: B[k][n] = Z[J + n][k] -> same load pattern with base J
    short8 a[4][2], b[4][2];
#pragma unroll
    for (int m = 0; m < 4; m++) {
#pragma unroll
        for (int kk = 0; kk < 2; kk++) {
            a[m][kk] = *(const short8*)(Zh + (size_t)(I + m * 16 + r) * 64 + kk * 32 + koff);
            b[m][kk] = *(const short8*)(Zh + (size_t)(J + m * 16 + r) * 64 + kk * 32 + koff);
        }
    }
    f32x4 acc[4][4];
#pragma unroll
    for (int m = 0; m < 4; m++)
#pragma unroll
        for (int n = 0; n < 4; n++) acc[m][n] = (f32x4){0.f, 0.f, 0.f, 0.f};

#pragma unroll
    for (int kk = 0; kk < 2; kk++)
#pragma unroll
        for (int m = 0; m < 4; m++)
#pragma unroll
            for (int n = 0; n < 4; n++)
                acc[m][n] = __builtin_amdgcn_mfma_f32_16x16x32_bf16(a[m][kk], b[n][kk],
                                                                    acc[m][n], 0, 0, 0);

    // C/D layout: col = lane&15, row = (lane>>4)*4 + reg   [m89-verified]
    int crow = (lane >> 4) * 4;
    int ccol = lane & 15;
#pragma unroll
    for (int m = 0; m < 4; m++)
#pragma unroll
        for (int rg = 0; rg < 4; rg++) {
            size_t row = (size_t)(I + m * 16 + crow + rg);
#pragma unroll
            for (int n = 0; n < 4; n++)
                C[row * 8192 + J + n * 16 + ccol] = acc[m][n][rg];
        }
}

extern "C" void kernel_launch(void* const* d_in, const int* in_sizes, int n_in,
                              void* d_out, int out_size, void* d_ws, size_t ws_size,
                              hipStream_t stream) {
    const float* x        = (const float*)d_in[0];
    const int*   adj_rows = (const int*)d_in[1];
    const int*   adj_cols = (const int*)d_in[2];
    const float* adj_vals = (const float*)d_in[3];
    const float* W1       = (const float*)d_in[4];
    const float* W2       = (const float*)d_in[5];
    const float* W3       = (const float*)d_in[6];
    const float* dense_W  = (const float*)d_in[7];
    const float* dense_b  = (const float*)d_in[8];
    const float* dense1_W = (const float*)d_in[9];
    const float* dense1_b = (const float*)d_in[10];

    // workspace layout
    char* p = (char*)d_ws;
    int* counts = (int*)p;   p += 8192 * 4;
    int* cursor = (int*)p;   p += 8192 * 4;
    int* offs   = (int*)p;   p += 8224 * 4;   // 8193 used, padded
    int* scol   = (int*)p;   p += (size_t)N_EDGES * 4;
    float* sval = (float*)p; p += (size_t)N_EDGES * 4;
    float* XW1  = (float*)p; p += (size_t)8192 * 256 * 4;
    float* Hid  = (float*)p; p += (size_t)8192 * 256 * 4;
    float* Tb   = (float*)p; p += (size_t)8192 * 256 * 4;
    float* Mb   = (float*)p; p += (size_t)8192 * 256 * 4;
    float* W23  = (float*)p; p += (size_t)256 * 256 * 4;
    __hip_bfloat16* Zh = (__hip_bfloat16*)p; p += (size_t)8192 * 64 * 2;

    // output layout: adj_rec [8192x8192], out6 [8192x6], mu [8192x64], logvar [8192x64]
    float* out     = (float*)d_out;
    float* adj_rec = out;
    float* out6    = out + (size_t)8192 * 8192;
    float* mu      = out6 + (size_t)8192 * 6;
    float* logvar  = mu + (size_t)8192 * 64;

    dim3 blk(16, 16);

    hipMemsetAsync(counts, 0, 2 * 8192 * 4, stream);  // counts + cursor
    k_hist<<<N_EDGES / 256, 256, 0, stream>>>(adj_rows, counts);
    k_scan<<<1, 1024, 0, stream>>>(counts, offs);
    k_scatter<<<N_EDGES / 256, 256, 0, stream>>>(adj_rows, adj_cols, adj_vals, offs, cursor,
                                                 scol, sval);
    k_concat_w23<<<256, 256, 0, stream>>>(W2, W3, W23);

    // XW1 = x @ W1
    k_gemm<<<dim3(4, 128), blk, 0, stream>>>(x, 512, W1, 256, XW1, 256, 512, nullptr);
    // hidden1 = relu(spmm(XW1))
    k_spmm<<<8192, 256, 0, stream>>>(offs, scol, sval, XW1, Hid, 1);
    // T = hidden1 @ [W2|W3]
    k_gemm<<<dim3(4, 128), blk, 0, stream>>>(Hid, 256, W23, 256, Tb, 256, 256, nullptr);
    // M = spmm(T)  -> [mu0 | logvar0]
    k_spmm<<<8192, 256, 0, stream>>>(offs, scol, sval, Tb, Mb, 0);
    // mu = M[:, :128] @ dense_W + dense_b ; logvar = M[:, 128:] @ dense_W + dense_b
    k_gemm<<<dim3(1, 128), blk, 0, stream>>>(Mb, 256, dense_W, 64, mu, 64, 128, dense_b);
    k_gemm<<<dim3(1, 128), blk, 0, stream>>>(Mb + 128, 256, dense_W, 64, logvar, 64, 128, dense_b);
    // out6 = mu @ dense1_W + dense1_b
    k_out6<<<32, 256, 0, stream>>>(mu, dense1_W, dense1_b, out6);
    // adj_rec = mu @ mu^T (bf16 MFMA, fp32 accumulate)
    k_f32_to_bf16<<<2048, 256, 0, stream>>>(mu, Zh, 8192 * 64);
    k_zzt_mfma<<<dim3(64, 64), dim3(256), 0, stream>>>(Zh, adj_rec);
}